// Round 6
// baseline (325.809 us; speedup 1.0000x reference)
//
#include <hip/hip_runtime.h>
#include <hip/hip_bf16.h>

#define BB 8
#define ND 12288
#define NU 49152
#define CI 64
#define CO 32
#define SP 9
#define NNZ 147456
#define KTOT (SP * CI)   // 576

using short8 = __attribute__((ext_vector_type(8))) short;
using f32x4  = __attribute__((ext_vector_type(4))) float;

// ---- workspace layout ----
// pooled_bf : [NU][BB][CI] bf16 = 50,331,648 B   (batch-inner for contiguous gathers)
// wbf       : [CO][KTOT] bf16   =     36,864 B
// cnt/start/fill/pcol/pval      : CSR scratch
#define OFF_WBF   ((size_t)BB * NU * CI * 2)
#define OFF_CNT   (OFF_WBF   + (size_t)CO * KTOT * 2)
#define OFF_START (OFF_CNT   + (size_t)NU * 4)
#define OFF_FILL  (OFF_START + (size_t)(NU + 1) * 4 + 4)
#define OFF_PCOL  (OFF_FILL  + (size_t)NU * 4)
#define OFF_PVAL  (OFF_PCOL  + (size_t)NNZ * 4)

static __device__ __forceinline__ unsigned short f2bf(float f) {
    __hip_bfloat16 h = __float2bfloat16(f);   // RNE
    return *reinterpret_cast<unsigned short*>(&h);
}

__global__ __launch_bounds__(256) void hist_kernel(
    const int* __restrict__ rows, int* __restrict__ cnt)
{
    const int i = blockIdx.x * 256 + threadIdx.x;
    atomicAdd(&cnt[rows[i]], 1);
}

__global__ __launch_bounds__(1024) void scan_kernel(
    const int* __restrict__ cnt, int* __restrict__ start, int* __restrict__ fill)
{
    __shared__ int sums[1024];
    const int t = threadIdx.x;
    const int base = t * (NU / 1024);
    int s = 0;
#pragma unroll
    for (int i = 0; i < NU / 1024; ++i) s += cnt[base + i];
    sums[t] = s;
    __syncthreads();
    for (int off = 1; off < 1024; off <<= 1) {
        const int add = (t >= off) ? sums[t - off] : 0;
        __syncthreads();
        sums[t] += add;
        __syncthreads();
    }
    int excl = sums[t] - s;
#pragma unroll
    for (int i = 0; i < NU / 1024; ++i) {
        const int c = cnt[base + i];
        start[base + i] = excl;
        fill[base + i]  = excl;
        excl += c;
    }
    if (t == 1023) start[NU] = sums[1023];
}

__global__ __launch_bounds__(256) void perm_kernel(
    const int* __restrict__ rows, const int* __restrict__ cols,
    const float* __restrict__ vals, int* __restrict__ fill,
    int* __restrict__ pcol, float* __restrict__ pval)
{
    const int i = blockIdx.x * 256 + threadIdx.x;
    const int pos = atomicAdd(&fill[rows[i]], 1);
    pcol[pos] = cols[i];
    pval[pos] = vals[i];
}

__global__ __launch_bounds__(256) void wcvt_kernel(
    const float* __restrict__ weight, unsigned short* __restrict__ wbf)
{
    const int i = blockIdx.x * 256 + threadIdx.x;
    wbf[i] = f2bf(weight[i]);
}

// one thread per (row, channel-quad): gather entries, f32 accumulate, bf16 store.
// pooled layout: [NU][BB][CI]
__global__ __launch_bounds__(256) void pool_kernel(
    const float* __restrict__ x, const int* __restrict__ start,
    const int* __restrict__ pcol, const float* __restrict__ pval,
    unsigned short* __restrict__ pooled)
{
    const int t   = blockIdx.x * 256 + threadIdx.x;
    const int row = t >> 4;
    const int cq  = (t & 15) << 2;
    const int s = start[row], e = start[row + 1];
    float4 acc[BB];
#pragma unroll
    for (int b = 0; b < BB; ++b) acc[b] = make_float4(0.f, 0.f, 0.f, 0.f);
    for (int j = s; j < e; ++j) {
        const int col = pcol[j];
        const float v = pval[j];
#pragma unroll
        for (int b = 0; b < BB; ++b) {
            const float4 xv = *(const float4*)(x + ((size_t)(b * ND + col) * CI + cq));
            acc[b].x = fmaf(v, xv.x, acc[b].x);
            acc[b].y = fmaf(v, xv.y, acc[b].y);
            acc[b].z = fmaf(v, xv.z, acc[b].z);
            acc[b].w = fmaf(v, xv.w, acc[b].w);
        }
    }
#pragma unroll
    for (int b = 0; b < BB; ++b) {
        uint2 pk;
        pk.x = (unsigned)f2bf(acc[b].x) | ((unsigned)f2bf(acc[b].y) << 16);
        pk.y = (unsigned)f2bf(acc[b].z) | ((unsigned)f2bf(acc[b].w) << 16);
        *(uint2*)(pooled + ((size_t)row * BB + b) * CI + cq) = pk;
    }
}

// MFMA conv: block = 512 threads = 8 waves; wave w = batch w, 16 vertices x 32 cols.
// All 9 spiral indices + all 18 A-fragments prefetched -> ~18 outstanding loads/wave.
// pooled [NU][BB][CI]: the 8 waves' gathers for one (vertex,s) are 8 adjacent 128B lines.
// C/D: col=lane&15 (out channel), row=(lane>>4)*4+reg (vertex) — verified in round 3.
__global__ __launch_bounds__(512) void conv_mfma(
    const unsigned short* __restrict__ pooled, const unsigned short* __restrict__ wbf,
    const int* __restrict__ spiral, const float* __restrict__ bias,
    float* __restrict__ out)
{
    const int tid  = threadIdx.x;
    const int b    = tid >> 6;        // wave index = batch
    const int lane = tid & 63;
    const int r    = lane & 15;
    const int kg   = lane >> 4;
    const int n0   = blockIdx.x * 16;
    const int n    = n0 + r;

    // prefetch spiral indices (9 independent loads)
    int gidx[SP];
#pragma unroll
    for (int s = 0; s < SP; ++s) gidx[s] = spiral[n * SP + s];

    // prefetch all A fragments (18 independent 16B loads)
    short8 a[SP][2];
#pragma unroll
    for (int s = 0; s < SP; ++s) {
        const unsigned short* arow = pooled + ((size_t)gidx[s] * BB + b) * CI + kg * 8;
        a[s][0] = *(const short8*)(arow);
        a[s][1] = *(const short8*)(arow + 32);
    }

    f32x4 acc0 = {0.f, 0.f, 0.f, 0.f};
    f32x4 acc1 = {0.f, 0.f, 0.f, 0.f};
    const unsigned short* w0 = wbf + (size_t)r        * KTOT + kg * 8;
    const unsigned short* w1 = wbf + (size_t)(16 + r) * KTOT + kg * 8;

#pragma unroll
    for (int s = 0; s < SP; ++s) {
        const short8 b00 = *(const short8*)(w0 + s * 64);
        const short8 b01 = *(const short8*)(w1 + s * 64);
        const short8 b10 = *(const short8*)(w0 + s * 64 + 32);
        const short8 b11 = *(const short8*)(w1 + s * 64 + 32);
        acc0 = __builtin_amdgcn_mfma_f32_16x16x32_bf16(a[s][0], b00, acc0, 0, 0, 0);
        acc1 = __builtin_amdgcn_mfma_f32_16x16x32_bf16(a[s][0], b01, acc1, 0, 0, 0);
        acc0 = __builtin_amdgcn_mfma_f32_16x16x32_bf16(a[s][1], b10, acc0, 0, 0, 0);
        acc1 = __builtin_amdgcn_mfma_f32_16x16x32_bf16(a[s][1], b11, acc1, 0, 0, 0);
    }

    const float bo0 = bias[r];
    const float bo1 = bias[16 + r];
    const size_t mbase = (size_t)b * NU + n0 + kg * 4;
#pragma unroll
    for (int reg = 0; reg < 4; ++reg) {
        const size_t m = mbase + reg;
        out[m * CO + r]      = fmaxf(acc0[reg] + bo0, 0.f);
        out[m * CO + 16 + r] = fmaxf(acc1[reg] + bo1, 0.f);
    }
}

extern "C" void kernel_launch(void* const* d_in, const int* in_sizes, int n_in,
                              void* d_out, int out_size, void* d_ws, size_t ws_size,
                              hipStream_t stream) {
    const float* x      = (const float*)d_in[0];
    const int*   rows   = (const int*)d_in[1];
    const int*   cols   = (const int*)d_in[2];
    const float* vals   = (const float*)d_in[3];
    const int*   spiral = (const int*)d_in[4];
    const float* weight = (const float*)d_in[5];
    const float* bias   = (const float*)d_in[6];
    float*       out    = (float*)d_out;

    char* ws = (char*)d_ws;
    unsigned short* pooled = (unsigned short*)ws;
    unsigned short* wbf    = (unsigned short*)(ws + OFF_WBF);
    int*   cnt    = (int*)(ws + OFF_CNT);
    int*   startp = (int*)(ws + OFF_START);
    int*   fill   = (int*)(ws + OFF_FILL);
    int*   pcol   = (int*)(ws + OFF_PCOL);
    float* pval   = (float*)(ws + OFF_PVAL);

    hipMemsetAsync(cnt, 0, (size_t)NU * 4, stream);

    hist_kernel<<<NNZ / 256, 256, 0, stream>>>(rows, cnt);
    scan_kernel<<<1, 1024, 0, stream>>>(cnt, startp, fill);
    perm_kernel<<<NNZ / 256, 256, 0, stream>>>(rows, cols, vals, fill, pcol, pval);
    wcvt_kernel<<<(CO * KTOT) / 256, 256, 0, stream>>>(weight, wbf);
    pool_kernel<<<(NU * 16) / 256, 256, 0, stream>>>(x, startp, pcol, pval, pooled);

    conv_mfma<<<NU / 16, 512, 0, stream>>>(pooled, wbf, spiral, bias, out);
}

// Round 9
// 248.598 us; speedup vs baseline: 1.3106x; 1.3106x over previous
//
#include <hip/hip_runtime.h>
#include <hip/hip_bf16.h>

#define BB 8
#define ND 12288
#define NU 49152
#define CI 64
#define CO 32
#define SP 9
#define NNZ 147456
#define KTOT (SP * CI)   // 576
#define KPAD 584         // padded LDS row (shorts): 1168B = 292 dwords, 292%32=4 -> ~2-way banks

using short8 = __attribute__((ext_vector_type(8))) short;
using f32x4  = __attribute__((ext_vector_type(4))) float;

// ---- workspace layout ----
// pooled_bf : [NU][BB][CI] bf16 = 50,331,648 B   (batch-inner: one vertex row = 1KB)
// wbf       : [CO][KTOT] bf16   =     36,864 B
// cnt/start/fill/pcol/pval      : CSR scratch
#define OFF_WBF   ((size_t)BB * NU * CI * 2)
#define OFF_CNT   (OFF_WBF   + (size_t)CO * KTOT * 2)
#define OFF_START (OFF_CNT   + (size_t)NU * 4)
#define OFF_FILL  (OFF_START + (size_t)(NU + 1) * 4 + 4)
#define OFF_PCOL  (OFF_FILL  + (size_t)NU * 4)
#define OFF_PVAL  (OFF_PCOL  + (size_t)NNZ * 4)

static __device__ __forceinline__ unsigned short f2bf(float f) {
    __hip_bfloat16 h = __float2bfloat16(f);   // RNE
    return *reinterpret_cast<unsigned short*>(&h);
}

__global__ __launch_bounds__(256) void hist_kernel(
    const int* __restrict__ rows, int* __restrict__ cnt)
{
    const int i = blockIdx.x * 256 + threadIdx.x;
    atomicAdd(&cnt[rows[i]], 1);
}

__global__ __launch_bounds__(1024) void scan_kernel(
    const int* __restrict__ cnt, int* __restrict__ start, int* __restrict__ fill)
{
    __shared__ int sums[1024];
    const int t = threadIdx.x;
    const int base = t * (NU / 1024);
    int s = 0;
#pragma unroll
    for (int i = 0; i < NU / 1024; ++i) s += cnt[base + i];
    sums[t] = s;
    __syncthreads();
    for (int off = 1; off < 1024; off <<= 1) {
        const int add = (t >= off) ? sums[t - off] : 0;
        __syncthreads();
        sums[t] += add;
        __syncthreads();
    }
    int excl = sums[t] - s;
#pragma unroll
    for (int i = 0; i < NU / 1024; ++i) {
        const int c = cnt[base + i];
        start[base + i] = excl;
        fill[base + i]  = excl;
        excl += c;
    }
    if (t == 1023) start[NU] = sums[1023];
}

__global__ __launch_bounds__(256) void perm_kernel(
    const int* __restrict__ rows, const int* __restrict__ cols,
    const float* __restrict__ vals, int* __restrict__ fill,
    int* __restrict__ pcol, float* __restrict__ pval)
{
    const int i = blockIdx.x * 256 + threadIdx.x;
    const int pos = atomicAdd(&fill[rows[i]], 1);
    pcol[pos] = cols[i];
    pval[pos] = vals[i];
}

__global__ __launch_bounds__(256) void wcvt_kernel(
    const float* __restrict__ weight, unsigned short* __restrict__ wbf)
{
    const int i = blockIdx.x * 256 + threadIdx.x;
    wbf[i] = f2bf(weight[i]);
}

// one thread per (row, channel-quad): gather entries, f32 accumulate, bf16 store.
// pooled layout: [NU][BB][CI]  (UNCHANGED this round for clean attribution)
__global__ __launch_bounds__(256) void pool_kernel(
    const float* __restrict__ x, const int* __restrict__ start,
    const int* __restrict__ pcol, const float* __restrict__ pval,
    unsigned short* __restrict__ pooled)
{
    const int t   = blockIdx.x * 256 + threadIdx.x;
    const int row = t >> 4;
    const int cq  = (t & 15) << 2;
    const int s = start[row], e = start[row + 1];
    float4 acc[BB];
#pragma unroll
    for (int b = 0; b < BB; ++b) acc[b] = make_float4(0.f, 0.f, 0.f, 0.f);
    for (int j = s; j < e; ++j) {
        const int col = pcol[j];
        const float v = pval[j];
#pragma unroll
        for (int b = 0; b < BB; ++b) {
            const float4 xv = *(const float4*)(x + ((size_t)(b * ND + col) * CI + cq));
            acc[b].x = fmaf(v, xv.x, acc[b].x);
            acc[b].y = fmaf(v, xv.y, acc[b].y);
            acc[b].z = fmaf(v, xv.z, acc[b].z);
            acc[b].w = fmaf(v, xv.w, acc[b].w);
        }
    }
#pragma unroll
    for (int b = 0; b < BB; ++b) {
        uint2 pk;
        pk.x = (unsigned)f2bf(acc[b].x) | ((unsigned)f2bf(acc[b].y) << 16);
        pk.y = (unsigned)f2bf(acc[b].z) | ((unsigned)f2bf(acc[b].w) << 16);
        *(uint2*)(pooled + ((size_t)row * BB + b) * CI + cq) = pk;
    }
}

// MFMA conv, round 7 delta (unmeasured; resubmitted):
//  - 18 NAMED A-fragment loads + sched_barrier(0): compiler cannot sink them ->
//    all gathers in flight concurrently (VGPR ~110-128 is the success signature).
//  - B operand staged in LDS (padded rows): removes 36 divergent global loads/wave
//    from the vector-memory pipe; ds_read_b128 at ~2-way bank aliasing (free).
__global__ __launch_bounds__(512) void conv_mfma(
    const unsigned short* __restrict__ pooled, const unsigned short* __restrict__ wbf,
    const int* __restrict__ spiral, const float* __restrict__ bias,
    float* __restrict__ out)
{
    __shared__ __align__(16) unsigned short wT[CO][KPAD];

    const int tid  = threadIdx.x;
    const int b    = tid >> 6;        // wave index = batch
    const int lane = tid & 63;
    const int r    = lane & 15;
    const int kg   = lane >> 4;
    const int n0   = blockIdx.x * 16;
    const int n    = n0 + r;

    // stage weights -> LDS (coalesced: wave covers 4 rows x 128B per j)
    {
        const int o = tid >> 4;       // 0..31
        const int c = tid & 15;       // 16 threads per row
#pragma unroll
        for (int j = 0; j < 9; ++j) {
            const int idx = (j * 16 + c) * 4;   // short offset 0..572
            *(uint2*)&wT[o][idx] = *(const uint2*)(wbf + (size_t)o * KTOT + idx);
        }
    }

    // spiral indices (9 independent, L1-amortized across the 8 waves)
    int g[SP];
#pragma unroll
    for (int s = 0; s < SP; ++s) g[s] = spiral[n * SP + s];

    const unsigned short* abase = pooled + (size_t)b * CI + (size_t)kg * 8;

    // 18 independent named A-fragment loads, pinned before compute
    short8 a0l,a0h,a1l,a1h,a2l,a2h,a3l,a3h,a4l,a4h,a5l,a5h,a6l,a6h,a7l,a7h,a8l,a8h;
#define LDA(vl, vh, s) \
    vl = *(const short8*)(abase + (size_t)g[s] * (BB * CI)); \
    vh = *(const short8*)(abase + (size_t)g[s] * (BB * CI) + 32)
    LDA(a0l,a0h,0); LDA(a1l,a1h,1); LDA(a2l,a2h,2); LDA(a3l,a3h,3);
    LDA(a4l,a4h,4); LDA(a5l,a5h,5); LDA(a6l,a6h,6); LDA(a7l,a7h,7);
    LDA(a8l,a8h,8);
#undef LDA
    __builtin_amdgcn_sched_barrier(0);   // nothing crosses: loads stay issued here

    __syncthreads();                     // wT ready (also drains the A loads once)

    f32x4 acc0 = {0.f, 0.f, 0.f, 0.f};
    f32x4 acc1 = {0.f, 0.f, 0.f, 0.f};
    const unsigned short* w0 = &wT[r][kg * 8];
    const unsigned short* w1 = &wT[16 + r][kg * 8];

#define STEP(al, ah, s) do { \
    const short8 b00 = *(const short8*)(w0 + (s) * 64); \
    const short8 b01 = *(const short8*)(w1 + (s) * 64); \
    const short8 b10 = *(const short8*)(w0 + (s) * 64 + 32); \
    const short8 b11 = *(const short8*)(w1 + (s) * 64 + 32); \
    acc0 = __builtin_amdgcn_mfma_f32_16x16x32_bf16(al, b00, acc0, 0, 0, 0); \
    acc1 = __builtin_amdgcn_mfma_f32_16x16x32_bf16(al, b01, acc1, 0, 0, 0); \
    acc0 = __builtin_amdgcn_mfma_f32_16x16x32_bf16(ah, b10, acc0, 0, 0, 0); \
    acc1 = __builtin_amdgcn_mfma_f32_16x16x32_bf16(ah, b11, acc1, 0, 0, 0); \
  } while (0)
    STEP(a0l,a0h,0); STEP(a1l,a1h,1); STEP(a2l,a2h,2); STEP(a3l,a3h,3);
    STEP(a4l,a4h,4); STEP(a5l,a5h,5); STEP(a6l,a6h,6); STEP(a7l,a7h,7);
    STEP(a8l,a8h,8);
#undef STEP

    const float bo0 = bias[r];
    const float bo1 = bias[16 + r];
    const size_t mbase = (size_t)b * NU + n0 + kg * 4;
#pragma unroll
    for (int reg = 0; reg < 4; ++reg) {
        const size_t m = mbase + reg;
        out[m * CO + r]      = fmaxf(acc0[reg] + bo0, 0.f);
        out[m * CO + 16 + r] = fmaxf(acc1[reg] + bo1, 0.f);
    }
}

extern "C" void kernel_launch(void* const* d_in, const int* in_sizes, int n_in,
                              void* d_out, int out_size, void* d_ws, size_t ws_size,
                              hipStream_t stream) {
    const float* x      = (const float*)d_in[0];
    const int*   rows   = (const int*)d_in[1];
    const int*   cols   = (const int*)d_in[2];
    const float* vals   = (const float*)d_in[3];
    const int*   spiral = (const int*)d_in[4];
    const float* weight = (const float*)d_in[5];
    const float* bias   = (const float*)d_in[6];
    float*       out    = (float*)d_out;

    char* ws = (char*)d_ws;
    unsigned short* pooled = (unsigned short*)ws;
    unsigned short* wbf    = (unsigned short*)(ws + OFF_WBF);
    int*   cnt    = (int*)(ws + OFF_CNT);
    int*   startp = (int*)(ws + OFF_START);
    int*   fill   = (int*)(ws + OFF_FILL);
    int*   pcol   = (int*)(ws + OFF_PCOL);
    float* pval   = (float*)(ws + OFF_PVAL);

    hipMemsetAsync(cnt, 0, (size_t)NU * 4, stream);

    hist_kernel<<<NNZ / 256, 256, 0, stream>>>(rows, cnt);
    scan_kernel<<<1, 1024, 0, stream>>>(cnt, startp, fill);
    perm_kernel<<<NNZ / 256, 256, 0, stream>>>(rows, cols, vals, fill, pcol, pval);
    wcvt_kernel<<<(CO * KTOT) / 256, 256, 0, stream>>>(weight, wbf);
    pool_kernel<<<(NU * 16) / 256, 256, 0, stream>>>(x, startp, pcol, pval, pooled);

    conv_mfma<<<NU / 16, 512, 0, stream>>>(pooled, wbf, spiral, bias, out);
}

// Round 10
// 245.764 us; speedup vs baseline: 1.3257x; 1.0115x over previous
//
#include <hip/hip_runtime.h>
#include <hip/hip_bf16.h>

#define BB 8
#define ND 12288
#define NU 49152
#define CI 64
#define CO 32
#define SP 9
#define NNZ 147456
#define KTOT (SP * CI)   // 576
#define KPAD 584         // padded LDS row (shorts): ~2-way banks on ds_read_b128

using short8 = __attribute__((ext_vector_type(8))) short;
using f32x4  = __attribute__((ext_vector_type(4))) float;

// ---- workspace layout ----
// pooled_bf : [NU][BB][CI] bf16 = 50,331,648 B
// wbf       : [CO][KTOT] bf16  =     36,864 B
// cnt[NU], start[NU+1](+pad), fill[NU] : ints
// pent      : [NNZ] int2 {col, val-bits} = 1,179,648 B
#define OFF_WBF   ((size_t)BB * NU * CI * 2)
#define OFF_CNT   (OFF_WBF   + (size_t)CO * KTOT * 2)
#define OFF_START (OFF_CNT   + (size_t)NU * 4)
#define OFF_FILL  (OFF_START + (size_t)(NU + 1) * 4 + 4)
#define OFF_PENT  (OFF_FILL  + (size_t)NU * 4)   // 8B-aligned by construction

static __device__ __forceinline__ unsigned short f2bf(float f) {
    __hip_bfloat16 h = __float2bfloat16(f);   // RNE
    return *reinterpret_cast<unsigned short*>(&h);
}

__global__ __launch_bounds__(256) void hist_kernel(
    const int* __restrict__ rows, int* __restrict__ cnt)
{
    const int i = blockIdx.x * 256 + threadIdx.x;
    atomicAdd(&cnt[rows[i]], 1);
}

// 1 block x 1024 threads; 48 bins/thread; wave-shuffle scan, 2 barriers.
__global__ __launch_bounds__(1024) void scan_kernel(
    const int* __restrict__ cnt, int* __restrict__ start, int* __restrict__ fill)
{
    __shared__ int wsum[16], woff[16];
    const int t = threadIdx.x, lane = t & 63, w = t >> 6;
    const int base = t * 48;
    int c[48];
    int s = 0;
#pragma unroll
    for (int i = 0; i < 48; ++i) { c[i] = cnt[base + i]; s += c[i]; }
    int incl = s;
#pragma unroll
    for (int d = 1; d < 64; d <<= 1) {
        const int v = __shfl_up(incl, d, 64);
        if (lane >= d) incl += v;
    }
    if (lane == 63) wsum[w] = incl;
    __syncthreads();
    if (w == 0 && lane < 16) {
        const int v = wsum[lane];
        int inc2 = v;
#pragma unroll
        for (int d = 1; d < 16; d <<= 1) {
            const int u = __shfl_up(inc2, d, 16);
            if (lane >= d) inc2 += u;
        }
        woff[lane] = inc2 - v;
    }
    __syncthreads();
    int run = woff[w] + incl - s;
#pragma unroll
    for (int i = 0; i < 48; ++i) {
        start[base + i] = run;
        fill[base + i]  = run;
        run += c[i];
    }
    if (t == 1023) start[NU] = run;
}

__global__ __launch_bounds__(256) void perm_kernel(
    const int* __restrict__ rows, const int* __restrict__ cols,
    const float* __restrict__ vals, int* __restrict__ fill,
    int2* __restrict__ pent)
{
    const int i = blockIdx.x * 256 + threadIdx.x;
    const int pos = atomicAdd(&fill[rows[i]], 1);
    int2 e;
    e.x = cols[i];
    e.y = __float_as_int(vals[i]);
    pent[pos] = e;   // one 8B scatter instead of two 4B
}

__global__ __launch_bounds__(256) void wcvt_kernel(
    const float* __restrict__ weight, unsigned short* __restrict__ wbf)
{
    const int i = blockIdx.x * 256 + threadIdx.x;
    wbf[i] = f2bf(weight[i]);
}

// one thread per (row, channel-quad); 2-entry unroll -> 16 independent float4
// loads in flight (pinned by sched_barrier), f32 accumulate, bf16 store.
__global__ __launch_bounds__(256) void pool_kernel(
    const float* __restrict__ x, const int* __restrict__ start,
    const int2* __restrict__ pent, unsigned short* __restrict__ pooled)
{
    const int t   = blockIdx.x * 256 + threadIdx.x;
    const int row = t >> 4;
    const int cq  = (t & 15) << 2;
    const int s = start[row], e = start[row + 1];
    float4 acc[BB];
#pragma unroll
    for (int b = 0; b < BB; ++b) acc[b] = make_float4(0.f, 0.f, 0.f, 0.f);

    int j = s;
    for (; j + 1 < e; j += 2) {
        const int2 e0 = pent[j], e1 = pent[j + 1];
        const float v0 = __int_as_float(e0.y), v1 = __int_as_float(e1.y);
        float4 xv0[BB], xv1[BB];
#pragma unroll
        for (int b = 0; b < BB; ++b)
            xv0[b] = *(const float4*)(x + ((size_t)(b * ND + e0.x) * CI + cq));
#pragma unroll
        for (int b = 0; b < BB; ++b)
            xv1[b] = *(const float4*)(x + ((size_t)(b * ND + e1.x) * CI + cq));
        __builtin_amdgcn_sched_barrier(0);
#pragma unroll
        for (int b = 0; b < BB; ++b) {
            acc[b].x = fmaf(v0, xv0[b].x, acc[b].x);
            acc[b].y = fmaf(v0, xv0[b].y, acc[b].y);
            acc[b].z = fmaf(v0, xv0[b].z, acc[b].z);
            acc[b].w = fmaf(v0, xv0[b].w, acc[b].w);
            acc[b].x = fmaf(v1, xv1[b].x, acc[b].x);
            acc[b].y = fmaf(v1, xv1[b].y, acc[b].y);
            acc[b].z = fmaf(v1, xv1[b].z, acc[b].z);
            acc[b].w = fmaf(v1, xv1[b].w, acc[b].w);
        }
    }
    if (j < e) {
        const int2 e0 = pent[j];
        const float v0 = __int_as_float(e0.y);
#pragma unroll
        for (int b = 0; b < BB; ++b) {
            const float4 xv = *(const float4*)(x + ((size_t)(b * ND + e0.x) * CI + cq));
            acc[b].x = fmaf(v0, xv.x, acc[b].x);
            acc[b].y = fmaf(v0, xv.y, acc[b].y);
            acc[b].z = fmaf(v0, xv.z, acc[b].z);
            acc[b].w = fmaf(v0, xv.w, acc[b].w);
        }
    }
#pragma unroll
    for (int b = 0; b < BB; ++b) {
        uint2 pk;
        pk.x = (unsigned)f2bf(acc[b].x) | ((unsigned)f2bf(acc[b].y) << 16);
        pk.y = (unsigned)f2bf(acc[b].z) | ((unsigned)f2bf(acc[b].w) << 16);
        *(uint2*)(pooled + ((size_t)row * BB + b) * CI + cq) = pk;
    }
}

// MFMA conv (round-9 structure, verified 75.8us) + ONE delta: non-temporal out
// stores (out is write-once streaming; keep it out of L2/L3 so pooled stays hot).
__global__ __launch_bounds__(512) void conv_mfma(
    const unsigned short* __restrict__ pooled, const unsigned short* __restrict__ wbf,
    const int* __restrict__ spiral, const float* __restrict__ bias,
    float* __restrict__ out)
{
    __shared__ __align__(16) unsigned short wT[CO][KPAD];

    const int tid  = threadIdx.x;
    const int b    = tid >> 6;        // wave index = batch
    const int lane = tid & 63;
    const int r    = lane & 15;
    const int kg   = lane >> 4;
    const int n0   = blockIdx.x * 16;
    const int n    = n0 + r;

    // stage weights -> LDS
    {
        const int o = tid >> 4;
        const int c = tid & 15;
#pragma unroll
        for (int j = 0; j < 9; ++j) {
            const int idx = (j * 16 + c) * 4;
            *(uint2*)&wT[o][idx] = *(const uint2*)(wbf + (size_t)o * KTOT + idx);
        }
    }

    int g[SP];
#pragma unroll
    for (int s = 0; s < SP; ++s) g[s] = spiral[n * SP + s];

    const unsigned short* abase = pooled + (size_t)b * CI + (size_t)kg * 8;

    short8 a0l,a0h,a1l,a1h,a2l,a2h,a3l,a3h,a4l,a4h,a5l,a5h,a6l,a6h,a7l,a7h,a8l,a8h;
#define LDA(vl, vh, s) \
    vl = *(const short8*)(abase + (size_t)g[s] * (BB * CI)); \
    vh = *(const short8*)(abase + (size_t)g[s] * (BB * CI) + 32)
    LDA(a0l,a0h,0); LDA(a1l,a1h,1); LDA(a2l,a2h,2); LDA(a3l,a3h,3);
    LDA(a4l,a4h,4); LDA(a5l,a5h,5); LDA(a6l,a6h,6); LDA(a7l,a7h,7);
    LDA(a8l,a8h,8);
#undef LDA
    __builtin_amdgcn_sched_barrier(0);

    __syncthreads();

    f32x4 acc0 = {0.f, 0.f, 0.f, 0.f};
    f32x4 acc1 = {0.f, 0.f, 0.f, 0.f};
    const unsigned short* w0 = &wT[r][kg * 8];
    const unsigned short* w1 = &wT[16 + r][kg * 8];

#define STEP(al, ah, s) do { \
    const short8 b00 = *(const short8*)(w0 + (s) * 64); \
    const short8 b01 = *(const short8*)(w1 + (s) * 64); \
    const short8 b10 = *(const short8*)(w0 + (s) * 64 + 32); \
    const short8 b11 = *(const short8*)(w1 + (s) * 64 + 32); \
    acc0 = __builtin_amdgcn_mfma_f32_16x16x32_bf16(al, b00, acc0, 0, 0, 0); \
    acc1 = __builtin_amdgcn_mfma_f32_16x16x32_bf16(al, b01, acc1, 0, 0, 0); \
    acc0 = __builtin_amdgcn_mfma_f32_16x16x32_bf16(ah, b10, acc0, 0, 0, 0); \
    acc1 = __builtin_amdgcn_mfma_f32_16x16x32_bf16(ah, b11, acc1, 0, 0, 0); \
  } while (0)
    STEP(a0l,a0h,0); STEP(a1l,a1h,1); STEP(a2l,a2h,2); STEP(a3l,a3h,3);
    STEP(a4l,a4h,4); STEP(a5l,a5h,5); STEP(a6l,a6h,6); STEP(a7l,a7h,7);
    STEP(a8l,a8h,8);
#undef STEP

    const float bo0 = bias[r];
    const float bo1 = bias[16 + r];
    const size_t mbase = (size_t)b * NU + n0 + kg * 4;
#pragma unroll
    for (int reg = 0; reg < 4; ++reg) {
        const size_t m = mbase + reg;
        __builtin_nontemporal_store(fmaxf(acc0[reg] + bo0, 0.f), out + m * CO + r);
        __builtin_nontemporal_store(fmaxf(acc1[reg] + bo1, 0.f), out + m * CO + 16 + r);
    }
}

extern "C" void kernel_launch(void* const* d_in, const int* in_sizes, int n_in,
                              void* d_out, int out_size, void* d_ws, size_t ws_size,
                              hipStream_t stream) {
    const float* x      = (const float*)d_in[0];
    const int*   rows   = (const int*)d_in[1];
    const int*   cols   = (const int*)d_in[2];
    const float* vals   = (const float*)d_in[3];
    const int*   spiral = (const int*)d_in[4];
    const float* weight = (const float*)d_in[5];
    const float* bias   = (const float*)d_in[6];
    float*       out    = (float*)d_out;

    char* ws = (char*)d_ws;
    unsigned short* pooled = (unsigned short*)ws;
    unsigned short* wbf    = (unsigned short*)(ws + OFF_WBF);
    int*   cnt    = (int*)(ws + OFF_CNT);
    int*   startp = (int*)(ws + OFF_START);
    int*   fill   = (int*)(ws + OFF_FILL);
    int2*  pent   = (int2*)(ws + OFF_PENT);

    hipMemsetAsync(cnt, 0, (size_t)NU * 4, stream);

    hist_kernel<<<NNZ / 256, 256, 0, stream>>>(rows, cnt);
    scan_kernel<<<1, 1024, 0, stream>>>(cnt, startp, fill);
    perm_kernel<<<NNZ / 256, 256, 0, stream>>>(rows, cols, vals, fill, pent);
    wcvt_kernel<<<(CO * KTOT) / 256, 256, 0, stream>>>(weight, wbf);
    pool_kernel<<<(NU * 16) / 256, 256, 0, stream>>>(x, startp, pent, pooled);

    conv_mfma<<<NU / 16, 512, 0, stream>>>(pooled, wbf, spiral, bias, out);
}

// Round 11
// 241.817 us; speedup vs baseline: 1.3473x; 1.0163x over previous
//
#include <hip/hip_runtime.h>
#include <hip/hip_bf16.h>

#define BB 8
#define ND 12288
#define NU 49152
#define CI 64
#define CO 32
#define SP 9
#define NNZ 147456
#define KTOT (SP * CI)   // 576
#define KPAD 584         // padded LDS row (shorts): ~2-way banks on ds_read_b128

using short8 = __attribute__((ext_vector_type(8))) short;
using f32x4  = __attribute__((ext_vector_type(4))) float;

// ---- workspace layout ----
// pooled_bf : [NU][BB][CI] bf16 = 50,331,648 B
// wbf       : [CO][KTOT] bf16  =     36,864 B
// cnt[NU], start[NU+1](+pad), fill[NU] : ints
// pent      : [NNZ] int2 {col, val-bits} = 1,179,648 B
// xbf       : [BB][ND][CI] bf16 = 12,582,912 B
#define OFF_WBF   ((size_t)BB * NU * CI * 2)
#define OFF_CNT   (OFF_WBF   + (size_t)CO * KTOT * 2)
#define OFF_START (OFF_CNT   + (size_t)NU * 4)
#define OFF_FILL  (OFF_START + (size_t)(NU + 1) * 4 + 4)
#define OFF_PENT  (OFF_FILL  + (size_t)NU * 4)
#define OFF_XBF   (OFF_PENT  + (size_t)NNZ * 8)

static __device__ __forceinline__ unsigned short f2bf(float f) {
    __hip_bfloat16 h = __float2bfloat16(f);   // RNE
    return *reinterpret_cast<unsigned short*>(&h);
}
static __device__ __forceinline__ float bflo(unsigned u) {  // low bf16 -> f32
    return __uint_as_float(u << 16);
}
static __device__ __forceinline__ float bfhi(unsigned u) {  // high bf16 -> f32
    return __uint_as_float(u & 0xffff0000u);
}

__global__ __launch_bounds__(256) void hist_kernel(
    const int* __restrict__ rows, int* __restrict__ cnt)
{
    const int i = blockIdx.x * 256 + threadIdx.x;
    atomicAdd(&cnt[rows[i]], 1);
}

// 1 block x 1024 threads; 48 bins/thread; wave-shuffle scan, 2 barriers.
__global__ __launch_bounds__(1024) void scan_kernel(
    const int* __restrict__ cnt, int* __restrict__ start, int* __restrict__ fill)
{
    __shared__ int wsum[16], woff[16];
    const int t = threadIdx.x, lane = t & 63, w = t >> 6;
    const int base = t * 48;
    int c[48];
    int s = 0;
#pragma unroll
    for (int i = 0; i < 48; ++i) { c[i] = cnt[base + i]; s += c[i]; }
    int incl = s;
#pragma unroll
    for (int d = 1; d < 64; d <<= 1) {
        const int v = __shfl_up(incl, d, 64);
        if (lane >= d) incl += v;
    }
    if (lane == 63) wsum[w] = incl;
    __syncthreads();
    if (w == 0 && lane < 16) {
        const int v = wsum[lane];
        int inc2 = v;
#pragma unroll
        for (int d = 1; d < 16; d <<= 1) {
            const int u = __shfl_up(inc2, d, 16);
            if (lane >= d) inc2 += u;
        }
        woff[lane] = inc2 - v;
    }
    __syncthreads();
    int run = woff[w] + incl - s;
#pragma unroll
    for (int i = 0; i < 48; ++i) {
        start[base + i] = run;
        fill[base + i]  = run;
        run += c[i];
    }
    if (t == 1023) start[NU] = run;
}

__global__ __launch_bounds__(256) void perm_kernel(
    const int* __restrict__ rows, const int* __restrict__ cols,
    const float* __restrict__ vals, int* __restrict__ fill,
    int2* __restrict__ pent)
{
    const int i = blockIdx.x * 256 + threadIdx.x;
    const int pos = atomicAdd(&fill[rows[i]], 1);
    int2 e;
    e.x = cols[i];
    e.y = __float_as_int(vals[i]);
    pent[pos] = e;
}

__global__ __launch_bounds__(256) void wcvt_kernel(
    const float* __restrict__ weight, unsigned short* __restrict__ wbf)
{
    const int i = blockIdx.x * 256 + threadIdx.x;
    wbf[i] = f2bf(weight[i]);
}

// x f32 -> bf16, streaming; 4 elems/thread
__global__ __launch_bounds__(256) void xcvt_kernel(
    const float* __restrict__ x, unsigned short* __restrict__ xbf)
{
    const int i = (blockIdx.x * 256 + threadIdx.x) * 4;
    const float4 v = *(const float4*)(x + i);
    uint2 pk;
    pk.x = (unsigned)f2bf(v.x) | ((unsigned)f2bf(v.y) << 16);
    pk.y = (unsigned)f2bf(v.z) | ((unsigned)f2bf(v.w) << 16);
    *(uint2*)(xbf + i) = pk;
}

// one thread per (row, channel-quad); bf16 x gathers (8B/batch), f32 accumulate.
__global__ __launch_bounds__(256) void pool_kernel(
    const unsigned short* __restrict__ xbf, const int* __restrict__ start,
    const int2* __restrict__ pent, unsigned short* __restrict__ pooled)
{
    const int t   = blockIdx.x * 256 + threadIdx.x;
    const int row = t >> 4;
    const int cq  = (t & 15) << 2;
    const int s = start[row], e = start[row + 1];
    float4 acc[BB];
#pragma unroll
    for (int b = 0; b < BB; ++b) acc[b] = make_float4(0.f, 0.f, 0.f, 0.f);

    int j = s;
    for (; j + 1 < e; j += 2) {
        const int2 e0 = pent[j], e1 = pent[j + 1];
        const float v0 = __int_as_float(e0.y), v1 = __int_as_float(e1.y);
        uint2 xv0[BB], xv1[BB];
#pragma unroll
        for (int b = 0; b < BB; ++b)
            xv0[b] = *(const uint2*)(xbf + ((size_t)(b * ND + e0.x) * CI + cq));
#pragma unroll
        for (int b = 0; b < BB; ++b)
            xv1[b] = *(const uint2*)(xbf + ((size_t)(b * ND + e1.x) * CI + cq));
        __builtin_amdgcn_sched_barrier(0);
#pragma unroll
        for (int b = 0; b < BB; ++b) {
            acc[b].x = fmaf(v0, bflo(xv0[b].x), acc[b].x);
            acc[b].y = fmaf(v0, bfhi(xv0[b].x), acc[b].y);
            acc[b].z = fmaf(v0, bflo(xv0[b].y), acc[b].z);
            acc[b].w = fmaf(v0, bfhi(xv0[b].y), acc[b].w);
            acc[b].x = fmaf(v1, bflo(xv1[b].x), acc[b].x);
            acc[b].y = fmaf(v1, bfhi(xv1[b].x), acc[b].y);
            acc[b].z = fmaf(v1, bflo(xv1[b].y), acc[b].z);
            acc[b].w = fmaf(v1, bfhi(xv1[b].y), acc[b].w);
        }
    }
    if (j < e) {
        const int2 e0 = pent[j];
        const float v0 = __int_as_float(e0.y);
#pragma unroll
        for (int b = 0; b < BB; ++b) {
            const uint2 xv = *(const uint2*)(xbf + ((size_t)(b * ND + e0.x) * CI + cq));
            acc[b].x = fmaf(v0, bflo(xv.x), acc[b].x);
            acc[b].y = fmaf(v0, bfhi(xv.x), acc[b].y);
            acc[b].z = fmaf(v0, bflo(xv.y), acc[b].z);
            acc[b].w = fmaf(v0, bfhi(xv.y), acc[b].w);
        }
    }
#pragma unroll
    for (int b = 0; b < BB; ++b) {
        uint2 pk;
        pk.x = (unsigned)f2bf(acc[b].x) | ((unsigned)f2bf(acc[b].y) << 16);
        pk.y = (unsigned)f2bf(acc[b].z) | ((unsigned)f2bf(acc[b].w) << 16);
        *(uint2*)(pooled + ((size_t)row * BB + b) * CI + cq) = pk;
    }
}

// MFMA conv: round-9 verified structure (75.8us), NT store reverted.
__global__ __launch_bounds__(512) void conv_mfma(
    const unsigned short* __restrict__ pooled, const unsigned short* __restrict__ wbf,
    const int* __restrict__ spiral, const float* __restrict__ bias,
    float* __restrict__ out)
{
    __shared__ __align__(16) unsigned short wT[CO][KPAD];

    const int tid  = threadIdx.x;
    const int b    = tid >> 6;        // wave index = batch
    const int lane = tid & 63;
    const int r    = lane & 15;
    const int kg   = lane >> 4;
    const int n0   = blockIdx.x * 16;
    const int n    = n0 + r;

    // stage weights -> LDS
    {
        const int o = tid >> 4;
        const int c = tid & 15;
#pragma unroll
        for (int j = 0; j < 9; ++j) {
            const int idx = (j * 16 + c) * 4;
            *(uint2*)&wT[o][idx] = *(const uint2*)(wbf + (size_t)o * KTOT + idx);
        }
    }

    int g[SP];
#pragma unroll
    for (int s = 0; s < SP; ++s) g[s] = spiral[n * SP + s];

    const unsigned short* abase = pooled + (size_t)b * CI + (size_t)kg * 8;

    short8 a0l,a0h,a1l,a1h,a2l,a2h,a3l,a3h,a4l,a4h,a5l,a5h,a6l,a6h,a7l,a7h,a8l,a8h;
#define LDA(vl, vh, s) \
    vl = *(const short8*)(abase + (size_t)g[s] * (BB * CI)); \
    vh = *(const short8*)(abase + (size_t)g[s] * (BB * CI) + 32)
    LDA(a0l,a0h,0); LDA(a1l,a1h,1); LDA(a2l,a2h,2); LDA(a3l,a3h,3);
    LDA(a4l,a4h,4); LDA(a5l,a5h,5); LDA(a6l,a6h,6); LDA(a7l,a7h,7);
    LDA(a8l,a8h,8);
#undef LDA
    __builtin_amdgcn_sched_barrier(0);

    __syncthreads();

    f32x4 acc0 = {0.f, 0.f, 0.f, 0.f};
    f32x4 acc1 = {0.f, 0.f, 0.f, 0.f};
    const unsigned short* w0 = &wT[r][kg * 8];
    const unsigned short* w1 = &wT[16 + r][kg * 8];

#define STEP(al, ah, s) do { \
    const short8 b00 = *(const short8*)(w0 + (s) * 64); \
    const short8 b01 = *(const short8*)(w1 + (s) * 64); \
    const short8 b10 = *(const short8*)(w0 + (s) * 64 + 32); \
    const short8 b11 = *(const short8*)(w1 + (s) * 64 + 32); \
    acc0 = __builtin_amdgcn_mfma_f32_16x16x32_bf16(al, b00, acc0, 0, 0, 0); \
    acc1 = __builtin_amdgcn_mfma_f32_16x16x32_bf16(al, b01, acc1, 0, 0, 0); \
    acc0 = __builtin_amdgcn_mfma_f32_16x16x32_bf16(ah, b10, acc0, 0, 0, 0); \
    acc1 = __builtin_amdgcn_mfma_f32_16x16x32_bf16(ah, b11, acc1, 0, 0, 0); \
  } while (0)
    STEP(a0l,a0h,0); STEP(a1l,a1h,1); STEP(a2l,a2h,2); STEP(a3l,a3h,3);
    STEP(a4l,a4h,4); STEP(a5l,a5h,5); STEP(a6l,a6h,6); STEP(a7l,a7h,7);
    STEP(a8l,a8h,8);
#undef STEP

    const float bo0 = bias[r];
    const float bo1 = bias[16 + r];
    const size_t mbase = (size_t)b * NU + n0 + kg * 4;
#pragma unroll
    for (int reg = 0; reg < 4; ++reg) {
        const size_t m = mbase + reg;
        out[m * CO + r]      = fmaxf(acc0[reg] + bo0, 0.f);
        out[m * CO + 16 + r] = fmaxf(acc1[reg] + bo1, 0.f);
    }
}

extern "C" void kernel_launch(void* const* d_in, const int* in_sizes, int n_in,
                              void* d_out, int out_size, void* d_ws, size_t ws_size,
                              hipStream_t stream) {
    const float* x      = (const float*)d_in[0];
    const int*   rows   = (const int*)d_in[1];
    const int*   cols   = (const int*)d_in[2];
    const float* vals   = (const float*)d_in[3];
    const int*   spiral = (const int*)d_in[4];
    const float* weight = (const float*)d_in[5];
    const float* bias   = (const float*)d_in[6];
    float*       out    = (float*)d_out;

    char* ws = (char*)d_ws;
    unsigned short* pooled = (unsigned short*)ws;
    unsigned short* wbf    = (unsigned short*)(ws + OFF_WBF);
    int*   cnt    = (int*)(ws + OFF_CNT);
    int*   startp = (int*)(ws + OFF_START);
    int*   fill   = (int*)(ws + OFF_FILL);
    int2*  pent   = (int2*)(ws + OFF_PENT);
    unsigned short* xbf = (unsigned short*)(ws + OFF_XBF);

    hipMemsetAsync(cnt, 0, (size_t)NU * 4, stream);

    hist_kernel<<<NNZ / 256, 256, 0, stream>>>(rows, cnt);
    scan_kernel<<<1, 1024, 0, stream>>>(cnt, startp, fill);
    perm_kernel<<<NNZ / 256, 256, 0, stream>>>(rows, cols, vals, fill, pent);
    wcvt_kernel<<<(CO * KTOT) / 256, 256, 0, stream>>>(weight, wbf);
    xcvt_kernel<<<(BB * ND * CI) / 1024, 256, 0, stream>>>(x, xbf);
    pool_kernel<<<(NU * 16) / 256, 256, 0, stream>>>(xbf, startp, pent, pooled);

    conv_mfma<<<NU / 16, 512, 0, stream>>>(pooled, wbf, spiral, bias, out);
}

// Round 12
// 224.156 us; speedup vs baseline: 1.4535x; 1.0788x over previous
//
#include <hip/hip_runtime.h>
#include <hip/hip_bf16.h>

#define BB 8
#define ND 12288
#define NU 49152
#define CI 64
#define CO 32
#define SP 9
#define NNZ 147456
#define KTOT (SP * CI)   // 576
#define KPAD 584         // padded LDS row (shorts): ~2-way banks on ds_read_b128

using short8 = __attribute__((ext_vector_type(8))) short;
using f32x4  = __attribute__((ext_vector_type(4))) float;

// ---- workspace layout ----
// pooled_bf : [NU][BB][CI] bf16 = 50,331,648 B
// wbf       : [CO][KTOT] bf16  =     36,864 B
// cnt[NU], start[NU+1](+pad), fill[NU] : ints
// pent      : [NNZ] int2 {col, val-bits} = 1,179,648 B
// xbf2      : [ND][BB][CI] bf16 (batch-inner transpose) = 12,582,912 B
#define OFF_WBF   ((size_t)BB * NU * CI * 2)
#define OFF_CNT   (OFF_WBF   + (size_t)CO * KTOT * 2)
#define OFF_START (OFF_CNT   + (size_t)NU * 4)
#define OFF_FILL  (OFF_START + (size_t)(NU + 1) * 4 + 4)
#define OFF_PENT  (OFF_FILL  + (size_t)NU * 4)
#define OFF_XBF   (((OFF_PENT + (size_t)NNZ * 8) + 15) & ~(size_t)15)  // 16B-aligned

static __device__ __forceinline__ unsigned short f2bf(float f) {
    __hip_bfloat16 h = __float2bfloat16(f);   // RNE
    return *reinterpret_cast<unsigned short*>(&h);
}
static __device__ __forceinline__ unsigned pk2(float a, float b) {
    return (unsigned)f2bf(a) | ((unsigned)f2bf(b) << 16);
}
static __device__ __forceinline__ float bflo(unsigned u) { return __uint_as_float(u << 16); }
static __device__ __forceinline__ float bfhi(unsigned u) { return __uint_as_float(u & 0xffff0000u); }

// prep: (a) x f32 [BB][ND][CI] -> bf16 transposed [ND][BB][CI]
//       (b) zero cnt   (c) weight f32 -> bf16 same layout
// grid covers BB*ND*8 = 786,432 threads (32B read / 16B write each)
__global__ __launch_bounds__(256) void prep_kernel(
    const float* __restrict__ x, const float* __restrict__ weight,
    unsigned short* __restrict__ xbf2, unsigned short* __restrict__ wbf,
    int* __restrict__ cnt)
{
    const int i = blockIdx.x * 256 + threadIdx.x;
    {
        const int b  = i / (ND * 8);
        const int r  = i - b * (ND * 8);
        const int n  = r >> 3;
        const int c8 = r & 7;
        const float4* px = (const float4*)(x + (((size_t)b * ND + n) * CI + c8 * 8));
        const float4 v0 = px[0], v1 = px[1];
        uint4 q;
        q.x = pk2(v0.x, v0.y); q.y = pk2(v0.z, v0.w);
        q.z = pk2(v1.x, v1.y); q.w = pk2(v1.z, v1.w);
        *(uint4*)(xbf2 + ((size_t)n * BB + b) * CI + c8 * 8) = q;
    }
    if (i < NU) cnt[i] = 0;
    if (i < (CO * KTOT) / 8) {
        const float4* pw = (const float4*)(weight + (size_t)i * 8);
        const float4 v0 = pw[0], v1 = pw[1];
        uint4 q;
        q.x = pk2(v0.x, v0.y); q.y = pk2(v0.z, v0.w);
        q.z = pk2(v1.x, v1.y); q.w = pk2(v1.z, v1.w);
        *(uint4*)(wbf + (size_t)i * 8) = q;
    }
}

__global__ __launch_bounds__(256) void hist_kernel(
    const int* __restrict__ rows, int* __restrict__ cnt)
{
    const int i = blockIdx.x * 256 + threadIdx.x;
    atomicAdd(&cnt[rows[i]], 1);
}

// 1 block x 1024 threads; 48 bins/thread; wave-shuffle scan, 2 barriers.
__global__ __launch_bounds__(1024) void scan_kernel(
    const int* __restrict__ cnt, int* __restrict__ start, int* __restrict__ fill)
{
    __shared__ int wsum[16], woff[16];
    const int t = threadIdx.x, lane = t & 63, w = t >> 6;
    const int base = t * 48;
    int c[48];
    int s = 0;
#pragma unroll
    for (int i = 0; i < 48; ++i) { c[i] = cnt[base + i]; s += c[i]; }
    int incl = s;
#pragma unroll
    for (int d = 1; d < 64; d <<= 1) {
        const int v = __shfl_up(incl, d, 64);
        if (lane >= d) incl += v;
    }
    if (lane == 63) wsum[w] = incl;
    __syncthreads();
    if (w == 0 && lane < 16) {
        const int v = wsum[lane];
        int inc2 = v;
#pragma unroll
        for (int d = 1; d < 16; d <<= 1) {
            const int u = __shfl_up(inc2, d, 16);
            if (lane >= d) inc2 += u;
        }
        woff[lane] = inc2 - v;
    }
    __syncthreads();
    int run = woff[w] + incl - s;
#pragma unroll
    for (int i = 0; i < 48; ++i) {
        start[base + i] = run;
        fill[base + i]  = run;
        run += c[i];
    }
    if (t == 1023) start[NU] = run;
}

__global__ __launch_bounds__(256) void perm_kernel(
    const int* __restrict__ rows, const int* __restrict__ cols,
    const float* __restrict__ vals, int* __restrict__ fill,
    int2* __restrict__ pent)
{
    const int i = blockIdx.x * 256 + threadIdx.x;
    const int pos = atomicAdd(&fill[rows[i]], 1);
    int2 e;
    e.x = cols[i];
    e.y = __float_as_int(vals[i]);
    pent[pos] = e;
}

// pool: 64 threads per row (wave = row -> uniform trip count, no divergence).
// lane = b*8 + c8; per entry ONE uint4 (16B) load; gather row = 1KB contiguous.
__global__ __launch_bounds__(256) void pool_kernel(
    const unsigned short* __restrict__ xbf2, const int* __restrict__ start,
    const int2* __restrict__ pent, unsigned short* __restrict__ pooled)
{
    const int tid  = threadIdx.x;
    const int row  = blockIdx.x * 4 + (tid >> 6);
    const int lane = tid & 63;
    const int b    = lane >> 3;
    const int c8   = lane & 7;
    const int s = start[row], e = start[row + 1];

    const unsigned short* xb = xbf2 + (size_t)b * CI + c8 * 8;
    float acc[8];
#pragma unroll
    for (int k = 0; k < 8; ++k) acc[k] = 0.f;

#define ACC8(q, v) do { \
    acc[0] = fmaf(v, bflo(q.x), acc[0]); acc[1] = fmaf(v, bfhi(q.x), acc[1]); \
    acc[2] = fmaf(v, bflo(q.y), acc[2]); acc[3] = fmaf(v, bfhi(q.y), acc[3]); \
    acc[4] = fmaf(v, bflo(q.z), acc[4]); acc[5] = fmaf(v, bfhi(q.z), acc[5]); \
    acc[6] = fmaf(v, bflo(q.w), acc[6]); acc[7] = fmaf(v, bfhi(q.w), acc[7]); \
  } while (0)

    int j = s;
    for (; j + 1 < e; j += 2) {
        const int2 e0 = pent[j], e1 = pent[j + 1];
        const float v0 = __int_as_float(e0.y), v1 = __int_as_float(e1.y);
        const uint4 q0 = *(const uint4*)(xb + (size_t)e0.x * (BB * CI));
        const uint4 q1 = *(const uint4*)(xb + (size_t)e1.x * (BB * CI));
        __builtin_amdgcn_sched_barrier(0);
        ACC8(q0, v0);
        ACC8(q1, v1);
    }
    if (j < e) {
        const int2 e0 = pent[j];
        const float v0 = __int_as_float(e0.y);
        const uint4 q0 = *(const uint4*)(xb + (size_t)e0.x * (BB * CI));
        ACC8(q0, v0);
    }
#undef ACC8

    uint4 o;
    o.x = pk2(acc[0], acc[1]); o.y = pk2(acc[2], acc[3]);
    o.z = pk2(acc[4], acc[5]); o.w = pk2(acc[6], acc[7]);
    *(uint4*)(pooled + ((size_t)row * BB + b) * CI + c8 * 8) = o;
}

// MFMA conv: round-9 verified structure (75.8us), untouched.
__global__ __launch_bounds__(512) void conv_mfma(
    const unsigned short* __restrict__ pooled, const unsigned short* __restrict__ wbf,
    const int* __restrict__ spiral, const float* __restrict__ bias,
    float* __restrict__ out)
{
    __shared__ __align__(16) unsigned short wT[CO][KPAD];

    const int tid  = threadIdx.x;
    const int b    = tid >> 6;        // wave index = batch
    const int lane = tid & 63;
    const int r    = lane & 15;
    const int kg   = lane >> 4;
    const int n0   = blockIdx.x * 16;
    const int n    = n0 + r;

    // stage weights -> LDS
    {
        const int o = tid >> 4;
        const int c = tid & 15;
#pragma unroll
        for (int j = 0; j < 9; ++j) {
            const int idx = (j * 16 + c) * 4;
            *(uint2*)&wT[o][idx] = *(const uint2*)(wbf + (size_t)o * KTOT + idx);
        }
    }

    int g[SP];
#pragma unroll
    for (int s = 0; s < SP; ++s) g[s] = spiral[n * SP + s];

    const unsigned short* abase = pooled + (size_t)b * CI + (size_t)kg * 8;

    short8 a0l,a0h,a1l,a1h,a2l,a2h,a3l,a3h,a4l,a4h,a5l,a5h,a6l,a6h,a7l,a7h,a8l,a8h;
#define LDA(vl, vh, s) \
    vl = *(const short8*)(abase + (size_t)g[s] * (BB * CI)); \
    vh = *(const short8*)(abase + (size_t)g[s] * (BB * CI) + 32)
    LDA(a0l,a0h,0); LDA(a1l,a1h,1); LDA(a2l,a2h,2); LDA(a3l,a3h,3);
    LDA(a4l,a4h,4); LDA(a5l,a5h,5); LDA(a6l,a6h,6); LDA(a7l,a7h,7);
    LDA(a8l,a8h,8);
#undef LDA
    __builtin_amdgcn_sched_barrier(0);

    __syncthreads();

    f32x4 acc0 = {0.f, 0.f, 0.f, 0.f};
    f32x4 acc1 = {0.f, 0.f, 0.f, 0.f};
    const unsigned short* w0 = &wT[r][kg * 8];
    const unsigned short* w1 = &wT[16 + r][kg * 8];

#define STEP(al, ah, s) do { \
    const short8 b00 = *(const short8*)(w0 + (s) * 64); \
    const short8 b01 = *(const short8*)(w1 + (s) * 64); \
    const short8 b10 = *(const short8*)(w0 + (s) * 64 + 32); \
    const short8 b11 = *(const short8*)(w1 + (s) * 64 + 32); \
    acc0 = __builtin_amdgcn_mfma_f32_16x16x32_bf16(al, b00, acc0, 0, 0, 0); \
    acc1 = __builtin_amdgcn_mfma_f32_16x16x32_bf16(al, b01, acc1, 0, 0, 0); \
    acc0 = __builtin_amdgcn_mfma_f32_16x16x32_bf16(ah, b10, acc0, 0, 0, 0); \
    acc1 = __builtin_amdgcn_mfma_f32_16x16x32_bf16(ah, b11, acc1, 0, 0, 0); \
  } while (0)
    STEP(a0l,a0h,0); STEP(a1l,a1h,1); STEP(a2l,a2h,2); STEP(a3l,a3h,3);
    STEP(a4l,a4h,4); STEP(a5l,a5h,5); STEP(a6l,a6h,6); STEP(a7l,a7h,7);
    STEP(a8l,a8h,8);
#undef STEP

    const float bo0 = bias[r];
    const float bo1 = bias[16 + r];
    const size_t mbase = (size_t)b * NU + n0 + kg * 4;
#pragma unroll
    for (int reg = 0; reg < 4; ++reg) {
        const size_t m = mbase + reg;
        out[m * CO + r]      = fmaxf(acc0[reg] + bo0, 0.f);
        out[m * CO + 16 + r] = fmaxf(acc1[reg] + bo1, 0.f);
    }
}

extern "C" void kernel_launch(void* const* d_in, const int* in_sizes, int n_in,
                              void* d_out, int out_size, void* d_ws, size_t ws_size,
                              hipStream_t stream) {
    const float* x      = (const float*)d_in[0];
    const int*   rows   = (const int*)d_in[1];
    const int*   cols   = (const int*)d_in[2];
    const float* vals   = (const float*)d_in[3];
    const int*   spiral = (const int*)d_in[4];
    const float* weight = (const float*)d_in[5];
    const float* bias   = (const float*)d_in[6];
    float*       out    = (float*)d_out;

    char* ws = (char*)d_ws;
    unsigned short* pooled = (unsigned short*)ws;
    unsigned short* wbf    = (unsigned short*)(ws + OFF_WBF);
    int*   cnt    = (int*)(ws + OFF_CNT);
    int*   startp = (int*)(ws + OFF_START);
    int*   fill   = (int*)(ws + OFF_FILL);
    int2*  pent   = (int2*)(ws + OFF_PENT);
    unsigned short* xbf2 = (unsigned short*)(ws + OFF_XBF);

    prep_kernel<<<(BB * ND * 8) / 256, 256, 0, stream>>>(x, weight, xbf2, wbf, cnt);
    hist_kernel<<<NNZ / 256, 256, 0, stream>>>(rows, cnt);
    scan_kernel<<<1, 1024, 0, stream>>>(cnt, startp, fill);
    perm_kernel<<<NNZ / 256, 256, 0, stream>>>(rows, cols, vals, fill, pent);
    pool_kernel<<<NU / 4, 256, 0, stream>>>(xbf2, startp, pent, pooled);

    conv_mfma<<<NU / 16, 512, 0, stream>>>(pooled, wbf, spiral, bias, out);
}

// Round 16
// 217.712 us; speedup vs baseline: 1.4965x; 1.0296x over previous
//
#include <hip/hip_runtime.h>
#include <hip/hip_bf16.h>

#define BB 8
#define ND 12288
#define NU 49152
#define CI 64
#define CO 32
#define SP 9
#define NNZ 147456
#define KTOT (SP * CI)   // 576
#define KPAD 584         // padded LDS row (shorts): ~2-way banks on ds_read_b128

using short8 = __attribute__((ext_vector_type(8))) short;
using f32x4  = __attribute__((ext_vector_type(4))) float;

// ---- workspace layout ----
// pooled_bf : [NU][BB][CI] bf16 = 50,331,648 B
// wbf       : [CO][KTOT] bf16  =     36,864 B
// cnt[NU], start[NU](+gctr), fill[NU] : ints
// pent      : [NNZ] int2 {col, val-bits} = 1,179,648 B
// xbf2      : [ND][BB][CI] bf16 (batch-inner transpose) = 12,582,912 B
#define OFF_WBF   ((size_t)BB * NU * CI * 2)
#define OFF_CNT   (OFF_WBF   + (size_t)CO * KTOT * 2)
#define OFF_START (OFF_CNT   + (size_t)NU * 4)
#define OFF_GCTR  (OFF_START + (size_t)NU * 4)          // 1 int + pad
#define OFF_FILL  (OFF_GCTR  + 16)
#define OFF_PENT  (OFF_FILL  + (size_t)NU * 4)
#define OFF_XBF   (((OFF_PENT + (size_t)NNZ * 8) + 15) & ~(size_t)15)  // 16B-aligned

static __device__ __forceinline__ unsigned short f2bf(float f) {
    __hip_bfloat16 h = __float2bfloat16(f);   // RNE
    return *reinterpret_cast<unsigned short*>(&h);
}
static __device__ __forceinline__ unsigned pk2(float a, float b) {
    return (unsigned)f2bf(a) | ((unsigned)f2bf(b) << 16);
}
static __device__ __forceinline__ float bflo(unsigned u) { return __uint_as_float(u << 16); }
static __device__ __forceinline__ float bfhi(unsigned u) { return __uint_as_float(u & 0xffff0000u); }

// prep: (a) x f32 [BB][ND][CI] -> bf16 transposed [ND][BB][CI]
//       (b) zero cnt + gctr   (c) weight f32 -> bf16
__global__ __launch_bounds__(256) void prep_kernel(
    const float* __restrict__ x, const float* __restrict__ weight,
    unsigned short* __restrict__ xbf2, unsigned short* __restrict__ wbf,
    int* __restrict__ cnt, int* __restrict__ gctr)
{
    const int i = blockIdx.x * 256 + threadIdx.x;
    {
        const int b  = i / (ND * 8);
        const int r  = i - b * (ND * 8);
        const int n  = r >> 3;
        const int c8 = r & 7;
        const float4* px = (const float4*)(x + (((size_t)b * ND + n) * CI + c8 * 8));
        const float4 v0 = px[0], v1 = px[1];
        uint4 q;
        q.x = pk2(v0.x, v0.y); q.y = pk2(v0.z, v0.w);
        q.z = pk2(v1.x, v1.y); q.w = pk2(v1.z, v1.w);
        *(uint4*)(xbf2 + ((size_t)n * BB + b) * CI + c8 * 8) = q;
    }
    if (i < NU) cnt[i] = 0;
    if (i == 0) *gctr = 0;
    if (i < (CO * KTOT) / 8) {
        const float4* pw = (const float4*)(weight + (size_t)i * 8);
        const float4 v0 = pw[0], v1 = pw[1];
        uint4 q;
        q.x = pk2(v0.x, v0.y); q.y = pk2(v0.z, v0.w);
        q.z = pk2(v1.x, v1.y); q.w = pk2(v1.z, v1.w);
        *(uint4*)(wbf + (size_t)i * 8) = q;
    }
}

__global__ __launch_bounds__(256) void hist_kernel(
    const int* __restrict__ rows, int* __restrict__ cnt)
{
    const int i = blockIdx.x * 256 + threadIdx.x;
    atomicAdd(&cnt[rows[i]], 1);
}

// UNORDERED segment allocator: replaces the serial single-block prefix scan.
// Segment order in pent is arbitrary — pool only reads [start, start+cnt).
__global__ __launch_bounds__(256) void alloc_kernel(
    const int* __restrict__ cnt, int* __restrict__ start, int* __restrict__ fill,
    int* __restrict__ gctr)
{
    const int i = blockIdx.x * 256 + threadIdx.x;
    const int c = cnt[i];
    const int pos = (c > 0) ? atomicAdd(gctr, c) : 0;
    start[i] = pos;
    fill[i]  = pos;
}

__global__ __launch_bounds__(256) void perm_kernel(
    const int* __restrict__ rows, const int* __restrict__ cols,
    const float* __restrict__ vals, int* __restrict__ fill,
    int2* __restrict__ pent)
{
    const int i = blockIdx.x * 256 + threadIdx.x;
    const int pos = atomicAdd(&fill[rows[i]], 1);
    int2 e;
    e.x = cols[i];
    e.y = __float_as_int(vals[i]);
    pent[pos] = e;
}

// pool: 64 threads per row; lane = b*8 + c8; 16B load per entry; segment end = s+cnt.
__global__ __launch_bounds__(256) void pool_kernel(
    const unsigned short* __restrict__ xbf2, const int* __restrict__ start,
    const int* __restrict__ cnt, const int2* __restrict__ pent,
    unsigned short* __restrict__ pooled)
{
    const int tid  = threadIdx.x;
    const int row  = blockIdx.x * 4 + (tid >> 6);
    const int lane = tid & 63;
    const int b    = lane >> 3;
    const int c8   = lane & 7;
    const int s = start[row];
    const int e = s + cnt[row];

    const unsigned short* xb = xbf2 + (size_t)b * CI + c8 * 8;
    float acc[8];
#pragma unroll
    for (int k = 0; k < 8; ++k) acc[k] = 0.f;

#define ACC8(q, v) do { \
    acc[0] = fmaf(v, bflo(q.x), acc[0]); acc[1] = fmaf(v, bfhi(q.x), acc[1]); \
    acc[2] = fmaf(v, bflo(q.y), acc[2]); acc[3] = fmaf(v, bfhi(q.y), acc[3]); \
    acc[4] = fmaf(v, bflo(q.z), acc[4]); acc[5] = fmaf(v, bfhi(q.z), acc[5]); \
    acc[6] = fmaf(v, bflo(q.w), acc[6]); acc[7] = fmaf(v, bfhi(q.w), acc[7]); \
  } while (0)

    int j = s;
    for (; j + 1 < e; j += 2) {
        const int2 e0 = pent[j], e1 = pent[j + 1];
        const float v0 = __int_as_float(e0.y), v1 = __int_as_float(e1.y);
        const uint4 q0 = *(const uint4*)(xb + (size_t)e0.x * (BB * CI));
        const uint4 q1 = *(const uint4*)(xb + (size_t)e1.x * (BB * CI));
        __builtin_amdgcn_sched_barrier(0);
        ACC8(q0, v0);
        ACC8(q1, v1);
    }
    if (j < e) {
        const int2 e0 = pent[j];
        const float v0 = __int_as_float(e0.y);
        const uint4 q0 = *(const uint4*)(xb + (size_t)e0.x * (BB * CI));
        ACC8(q0, v0);
    }
#undef ACC8

    uint4 o;
    o.x = pk2(acc[0], acc[1]); o.y = pk2(acc[2], acc[3]);
    o.z = pk2(acc[4], acc[5]); o.w = pk2(acc[6], acc[7]);
    *(uint4*)(pooled + ((size_t)row * BB + b) * CI + c8 * 8) = o;
}

// MFMA conv: round-9 verified structure (75.8us), untouched.
__global__ __launch_bounds__(512) void conv_mfma(
    const unsigned short* __restrict__ pooled, const unsigned short* __restrict__ wbf,
    const int* __restrict__ spiral, const float* __restrict__ bias,
    float* __restrict__ out)
{
    __shared__ __align__(16) unsigned short wT[CO][KPAD];

    const int tid  = threadIdx.x;
    const int b    = tid >> 6;        // wave index = batch
    const int lane = tid & 63;
    const int r    = lane & 15;
    const int kg   = lane >> 4;
    const int n0   = blockIdx.x * 16;
    const int n    = n0 + r;

    // stage weights -> LDS
    {
        const int o = tid >> 4;
        const int c = tid & 15;
#pragma unroll
        for (int j = 0; j < 9; ++j) {
            const int idx = (j * 16 + c) * 4;
            *(uint2*)&wT[o][idx] = *(const uint2*)(wbf + (size_t)o * KTOT + idx);
        }
    }

    int g[SP];
#pragma unroll
    for (int s = 0; s < SP; ++s) g[s] = spiral[n * SP + s];

    const unsigned short* abase = pooled + (size_t)b * CI + (size_t)kg * 8;

    short8 a0l,a0h,a1l,a1h,a2l,a2h,a3l,a3h,a4l,a4h,a5l,a5h,a6l,a6h,a7l,a7h,a8l,a8h;
#define LDA(vl, vh, s) \
    vl = *(const short8*)(abase + (size_t)g[s] * (BB * CI)); \
    vh = *(const short8*)(abase + (size_t)g[s] * (BB * CI) + 32)
    LDA(a0l,a0h,0); LDA(a1l,a1h,1); LDA(a2l,a2h,2); LDA(a3l,a3h,3);
    LDA(a4l,a4h,4); LDA(a5l,a5h,5); LDA(a6l,a6h,6); LDA(a7l,a7h,7);
    LDA(a8l,a8h,8);
#undef LDA
    __builtin_amdgcn_sched_barrier(0);

    __syncthreads();

    f32x4 acc0 = {0.f, 0.f, 0.f, 0.f};
    f32x4 acc1 = {0.f, 0.f, 0.f, 0.f};
    const unsigned short* w0 = &wT[r][kg * 8];
    const unsigned short* w1 = &wT[16 + r][kg * 8];

#define STEP(al, ah, s) do { \
    const short8 b00 = *(const short8*)(w0 + (s) * 64); \
    const short8 b01 = *(const short8*)(w1 + (s) * 64); \
    const short8 b10 = *(const short8*)(w0 + (s) * 64 + 32); \
    const short8 b11 = *(const short8*)(w1 + (s) * 64 + 32); \
    acc0 = __builtin_amdgcn_mfma_f32_16x16x32_bf16(al, b00, acc0, 0, 0, 0); \
    acc1 = __builtin_amdgcn_mfma_f32_16x16x32_bf16(al, b01, acc1, 0, 0, 0); \
    acc0 = __builtin_amdgcn_mfma_f32_16x16x32_bf16(ah, b10, acc0, 0, 0, 0); \
    acc1 = __builtin_amdgcn_mfma_f32_16x16x32_bf16(ah, b11, acc1, 0, 0, 0); \
  } while (0)
    STEP(a0l,a0h,0); STEP(a1l,a1h,1); STEP(a2l,a2h,2); STEP(a3l,a3h,3);
    STEP(a4l,a4h,4); STEP(a5l,a5h,5); STEP(a6l,a6h,6); STEP(a7l,a7h,7);
    STEP(a8l,a8h,8);
#undef STEP

    const float bo0 = bias[r];
    const float bo1 = bias[16 + r];
    const size_t mbase = (size_t)b * NU + n0 + kg * 4;
#pragma unroll
    for (int reg = 0; reg < 4; ++reg) {
        const size_t m = mbase + reg;
        out[m * CO + r]      = fmaxf(acc0[reg] + bo0, 0.f);
        out[m * CO + 16 + r] = fmaxf(acc1[reg] + bo1, 0.f);
    }
}

extern "C" void kernel_launch(void* const* d_in, const int* in_sizes, int n_in,
                              void* d_out, int out_size, void* d_ws, size_t ws_size,
                              hipStream_t stream) {
    const float* x      = (const float*)d_in[0];
    const int*   rows   = (const int*)d_in[1];
    const int*   cols   = (const int*)d_in[2];
    const float* vals   = (const float*)d_in[3];
    const int*   spiral = (const int*)d_in[4];
    const float* weight = (const float*)d_in[5];
    const float* bias   = (const float*)d_in[6];
    float*       out    = (float*)d_out;

    char* ws = (char*)d_ws;
    unsigned short* pooled = (unsigned short*)ws;
    unsigned short* wbf    = (unsigned short*)(ws + OFF_WBF);
    int*   cnt    = (int*)(ws + OFF_CNT);
    int*   startp = (int*)(ws + OFF_START);
    int*   gctr   = (int*)(ws + OFF_GCTR);
    int*   fill   = (int*)(ws + OFF_FILL);
    int2*  pent   = (int2*)(ws + OFF_PENT);
    unsigned short* xbf2 = (unsigned short*)(ws + OFF_XBF);

    prep_kernel<<<(BB * ND * 8) / 256, 256, 0, stream>>>(x, weight, xbf2, wbf, cnt, gctr);
    hist_kernel<<<NNZ / 256, 256, 0, stream>>>(rows, cnt);
    alloc_kernel<<<NU / 256, 256, 0, stream>>>(cnt, startp, fill, gctr);
    perm_kernel<<<NNZ / 256, 256, 0, stream>>>(rows, cols, vals, fill, pent);
    pool_kernel<<<NU / 4, 256, 0, stream>>>(xbf2, startp, cnt, pent, pooled);

    conv_mfma<<<NU / 16, 512, 0, stream>>>(pooled, wbf, spiral, bias, out);
}